// Round 1
// baseline (9173.757 us; speedup 1.0000x reference)
//
#include <hip/hip_runtime.h>
#include <math.h>

#define HH 768
#define FF 3072
#define NL 12
#define NH 12
#define DH 64
#define BB 4
#define LL 512
#define SS 8
#define MM (BB*LL)   // 2048

// ---------------- prep: valid_len, seg ids ----------------
__global__ void prep_kernel(const int* __restrict__ am, const int* __restrict__ bos,
                            int* __restrict__ seg, int* __restrict__ vl) {
  int b = blockIdx.x;
  int t = threadIdx.x;            // 512 threads
  __shared__ int red[512];
  red[t] = am[b*LL + t];
  __syncthreads();
  for (int off = 256; off > 0; off >>= 1) {
    if (t < off) red[t] += red[t+off];
    __syncthreads();
  }
  if (t == 0) vl[b] = red[0];
  int cnt = 0;
  #pragma unroll
  for (int s = 0; s < SS; s++) cnt += (bos[b*SS + s] <= t) ? 1 : 0;
  seg[b*LL + t] = cnt - 1;
}

// ---------------- embedding + LayerNorm ----------------
__global__ __launch_bounds__(256) void embed_ln_kernel(
    const float* __restrict__ word_emb, const float* __restrict__ pos_emb,
    const float* __restrict__ type_emb, const float* __restrict__ g,
    const float* __restrict__ bta, const int* __restrict__ ids,
    const int* __restrict__ tts, float* __restrict__ x)
{
  int row = blockIdx.x;           // 0..2047
  int l = row & (LL-1);
  int t = threadIdx.x;
  int id = ids[row];
  int ty = tts[row];
  float v[3];
  float s = 0.f, sq = 0.f;
  #pragma unroll
  for (int j = 0; j < 3; j++) {
    int c = t + j*256;
    float val = word_emb[(size_t)id*HH + c] + pos_emb[l*HH + c] + type_emb[ty*HH + c];
    v[j] = val; s += val; sq += val*val;
  }
  __shared__ float rs[256], rq[256];
  rs[t] = s; rq[t] = sq;
  __syncthreads();
  for (int off = 128; off > 0; off >>= 1) {
    if (t < off) { rs[t] += rs[t+off]; rq[t] += rq[t+off]; }
    __syncthreads();
  }
  float mean = rs[0] / HH;
  float var  = rq[0] / HH - mean*mean;
  float inv  = rsqrtf(var + 1e-12f);
  #pragma unroll
  for (int j = 0; j < 3; j++) {
    int c = t + j*256;
    x[(size_t)row*HH + c] = (v[j]-mean)*inv*g[c] + bta[c];
  }
}

// ---------------- residual + LayerNorm (in-place on x) ----------------
__global__ __launch_bounds__(256) void add_ln_kernel(
    const float* __restrict__ xin, const float* __restrict__ y,
    const float* __restrict__ g, const float* __restrict__ bta,
    float* __restrict__ xout)
{
  int row = blockIdx.x;
  int t = threadIdx.x;
  float v[3];
  float s = 0.f, sq = 0.f;
  #pragma unroll
  for (int j = 0; j < 3; j++) {
    int c = t + j*256;
    float val = xin[(size_t)row*HH + c] + y[(size_t)row*HH + c];
    v[j] = val; s += val; sq += val*val;
  }
  __shared__ float rs[256], rq[256];
  rs[t] = s; rq[t] = sq;
  __syncthreads();
  for (int off = 128; off > 0; off >>= 1) {
    if (t < off) { rs[t] += rs[t+off]; rq[t] += rq[t+off]; }
    __syncthreads();
  }
  float mean = rs[0] / HH;
  float var  = rq[0] / HH - mean*mean;
  float inv  = rsqrtf(var + 1e-12f);
  #pragma unroll
  for (int j = 0; j < 3; j++) {
    int c = t + j*256;
    xout[(size_t)row*HH + c] = (v[j]-mean)*inv*g[c] + bta[c];
  }
}

// ---------------- f32 tiled GEMM: C = A(MxK) @ B(KxN) + bias, optional GELU ----------------
// 64x64 tile, BK=16, 256 threads, 4x4 micro-tile per thread.
template<int ACT>
__global__ __launch_bounds__(256) void gemm_bias(
    const float* __restrict__ A, const float* __restrict__ Bm,
    const float* __restrict__ bias, float* __restrict__ C,
    int M, int N, int K)
{
  __shared__ float As[16][64];   // transposed: As[k][m]
  __shared__ float Bs[16][64];   // Bs[k][n]
  const int tid = threadIdx.x;
  const int m0 = blockIdx.y * 64, n0 = blockIdx.x * 64;
  const int tx = tid & 15, ty = tid >> 4;
  const int alm = tid >> 2, alk = (tid & 3) << 2;   // A: row, k-chunk
  const int blk = tid >> 4, bln = (tid & 15) << 2;  // B: k-row, n-chunk
  float acc[4][4] = {};

  for (int k0 = 0; k0 < K; k0 += 16) {
    float4 av = *(const float4*)&A[(size_t)(m0+alm)*K + k0 + alk];
    As[alk+0][alm] = av.x; As[alk+1][alm] = av.y;
    As[alk+2][alm] = av.z; As[alk+3][alm] = av.w;
    *(float4*)&Bs[blk][bln] = *(const float4*)&Bm[(size_t)(k0+blk)*N + n0 + bln];
    __syncthreads();
    #pragma unroll
    for (int kk = 0; kk < 16; kk++) {
      float4 a4 = *(const float4*)&As[kk][ty << 2];
      float4 b4 = *(const float4*)&Bs[kk][tx << 2];
      float aa[4] = {a4.x, a4.y, a4.z, a4.w};
      float bb[4] = {b4.x, b4.y, b4.z, b4.w};
      #pragma unroll
      for (int i = 0; i < 4; i++)
        #pragma unroll
        for (int j = 0; j < 4; j++)
          acc[i][j] = fmaf(aa[i], bb[j], acc[i][j]);
    }
    __syncthreads();
  }

  #pragma unroll
  for (int i = 0; i < 4; i++) {
    int mr = m0 + (ty << 2) + i;
    #pragma unroll
    for (int j = 0; j < 4; j++) {
      int nc = n0 + (tx << 2) + j;
      float val = acc[i][j] + bias[nc];
      if (ACT == 1) val = 0.5f * val * (1.0f + erff(val * 0.70710678118654752f));
      C[(size_t)mr*N + nc] = val;
    }
  }
}

// ---------------- flash attention, f32 ----------------
// grid: (L/64, NH, B); block 256. Each block: 64 q-rows of one head.
__global__ __launch_bounds__(256) void attn_kernel(
    const float* __restrict__ Q, const float* __restrict__ Kp, const float* __restrict__ Vp,
    float* __restrict__ ctx, const int* __restrict__ seg, const int* __restrict__ vl,
    const int* __restrict__ bos)
{
  const int q0 = blockIdx.x * 64;
  const int h  = blockIdx.y;
  const int b  = blockIdx.z;
  const int tid = threadIdx.x;

  __shared__ float Qs[64][65];
  __shared__ float Ks[64][65];
  __shared__ float Vs[64][65];
  __shared__ float Sc[64][65];
  __shared__ float mrow[64], lrow[64], srow[64];
  __shared__ int   segk[64];

  // load Q tile (64x64)
  #pragma unroll
  for (int j = 0; j < 4; j++) {
    int r = (tid >> 4) + j*16;
    int c = (tid & 15) << 2;
    float4 qv = *(const float4*)&Q[((size_t)(b*LL + q0 + r))*HH + h*DH + c];
    Qs[r][c] = qv.x; Qs[r][c+1] = qv.y; Qs[r][c+2] = qv.z; Qs[r][c+3] = qv.w;
  }
  if (tid < 64) { mrow[tid] = -1e30f; lrow[tid] = 0.f; }

  const int q  = tid & 63;
  const int db = tid >> 6;       // d-block 0..3 (16 cols each)
  const int qg = q0 + q;
  const int vlb = vl[b];
  const int hist = bos[b*SS];
  const int myseg = seg[b*LL + qg];
  const bool qvalid = qg < vlb;

  float o[16];
  #pragma unroll
  for (int j = 0; j < 16; j++) o[j] = 0.f;

  for (int k0 = 0; k0 < LL; k0 += 64) {
    // stage K,V tiles
    #pragma unroll
    for (int j = 0; j < 4; j++) {
      int r = (tid >> 4) + j*16;
      int c = (tid & 15) << 2;
      size_t base = ((size_t)(b*LL + k0 + r))*HH + h*DH + c;
      float4 kv = *(const float4*)&Kp[base];
      Ks[r][c] = kv.x; Ks[r][c+1] = kv.y; Ks[r][c+2] = kv.z; Ks[r][c+3] = kv.w;
      float4 vv = *(const float4*)&Vp[base];
      Vs[r][c] = vv.x; Vs[r][c+1] = vv.y; Vs[r][c+2] = vv.z; Vs[r][c+3] = vv.w;
    }
    if (tid < 64) segk[tid] = seg[b*LL + k0 + tid];
    __syncthreads();

    // scores: each thread 16 (q,k) dots
    #pragma unroll
    for (int jj = 0; jj < 16; jj++) {
      int k = db + (jj << 2);
      float s_ = 0.f;
      #pragma unroll
      for (int d = 0; d < 64; d++) s_ = fmaf(Qs[q][d], Ks[k][d], s_);
      int kg = k0 + k;
      bool kvalid = kg < vlb;
      bool ok = qvalid && kvalid && ((qg < hist) || (kg < hist) || (myseg == segk[k]));
      Sc[q][k] = s_ * 0.125f + (ok ? 0.f : -10000.f);
    }
    __syncthreads();

    // online softmax row update (wave 0)
    if (tid < 64) {
      float mold = mrow[tid];
      float mx = mold;
      for (int k = 0; k < 64; k++) mx = fmaxf(mx, Sc[tid][k]);
      float scl = expf(mold - mx);
      float sum = 0.f;
      for (int k = 0; k < 64; k++) {
        float p = expf(Sc[tid][k] - mx);
        Sc[tid][k] = p;
        sum += p;
      }
      mrow[tid] = mx;
      lrow[tid] = lrow[tid]*scl + sum;
      srow[tid] = scl;
    }
    __syncthreads();

    // accumulate O
    float scl = srow[q];
    #pragma unroll
    for (int j = 0; j < 16; j++) o[j] *= scl;
    for (int k = 0; k < 64; k++) {
      float p = Sc[q][k];
      #pragma unroll
      for (int j = 0; j < 16; j++)
        o[j] = fmaf(p, Vs[k][(db << 4) + j], o[j]);
    }
    __syncthreads();
  }

  float invl = 1.0f / lrow[q];
  #pragma unroll
  for (int j = 0; j < 16; j++)
    ctx[((size_t)(b*LL + q0 + q))*HH + h*DH + (db << 4) + j] = o[j] * invl;
}

// ---------------- final pooling ----------------
__global__ __launch_bounds__(256) void rowdot_kernel(const float* __restrict__ x,
                                                     const float* __restrict__ w,
                                                     float* __restrict__ rd) {
  int row = blockIdx.x;
  int t = threadIdx.x;
  float s = 0.f;
  #pragma unroll
  for (int j = 0; j < 3; j++) {
    int c = t + j*256;
    s = fmaf(x[(size_t)row*HH + c], w[c], s);
  }
  __shared__ float red[256];
  red[t] = s;
  __syncthreads();
  for (int off = 128; off > 0; off >>= 1) {
    if (t < off) red[t] += red[t+off];
    __syncthreads();
  }
  if (t == 0) rd[row] = red[0];
}

__global__ void logits_kernel(const float* __restrict__ rd, const int* __restrict__ bos,
                              const int* __restrict__ vl, const float* __restrict__ fcb,
                              float* __restrict__ out) {
  int i = threadIdx.x;
  if (i >= BB*SS) return;
  int b = i / SS, s = i % SS;
  int start = bos[b*SS + s];
  int end   = (s == SS-1) ? vl[b] : bos[b*SS + s + 1];
  float sum = 0.f;
  for (int t = start; t < end; t++) sum += rd[b*LL + t];
  out[i] = sum / (float)(end - start) + fcb[0];
}

extern "C" void kernel_launch(void* const* d_in, const int* in_sizes, int n_in,
                              void* d_out, int out_size, void* d_ws, size_t ws_size,
                              hipStream_t stream) {
  const float* word_emb  = (const float*)d_in[0];
  const float* pos_emb   = (const float*)d_in[1];
  const float* type_emb  = (const float*)d_in[2];
  const float* emb_ln_g  = (const float*)d_in[3];
  const float* emb_ln_b  = (const float*)d_in[4];
  const float* Wq        = (const float*)d_in[5];
  const float* bq        = (const float*)d_in[6];
  const float* Wk        = (const float*)d_in[7];
  const float* bk        = (const float*)d_in[8];
  const float* Wv        = (const float*)d_in[9];
  const float* bv        = (const float*)d_in[10];
  const float* Wo        = (const float*)d_in[11];
  const float* bo        = (const float*)d_in[12];
  const float* attn_ln_g = (const float*)d_in[13];
  const float* attn_ln_b = (const float*)d_in[14];
  const float* W1        = (const float*)d_in[15];
  const float* b1        = (const float*)d_in[16];
  const float* W2        = (const float*)d_in[17];
  const float* b2        = (const float*)d_in[18];
  const float* ffn_ln_g  = (const float*)d_in[19];
  const float* ffn_ln_b  = (const float*)d_in[20];
  const float* fc_w      = (const float*)d_in[21];
  const float* fc_b      = (const float*)d_in[22];
  const int* input_ids   = (const int*)d_in[23];
  const int* token_type  = (const int*)d_in[24];
  const int* am          = (const int*)d_in[25];
  const int* bos         = (const int*)d_in[26];
  float* out = (float*)d_out;

  char* w = (char*)d_ws;
  float* x    = (float*)w; w += (size_t)MM*HH*4;
  float* qb   = (float*)w; w += (size_t)MM*HH*4;
  float* kb   = (float*)w; w += (size_t)MM*HH*4;
  float* vb   = (float*)w; w += (size_t)MM*HH*4;
  float* ctxb = (float*)w; w += (size_t)MM*HH*4;
  float* tmp  = (float*)w; w += (size_t)MM*HH*4;
  float* hbuf = (float*)w; w += (size_t)MM*FF*4;
  float* rd   = (float*)w; w += (size_t)MM*4;
  int*   seg  = (int*)w;   w += (size_t)MM*4;
  int*   vl   = (int*)w;   w += 64;

  prep_kernel<<<BB, 512, 0, stream>>>(am, bos, seg, vl);
  embed_ln_kernel<<<MM, 256, 0, stream>>>(word_emb, pos_emb, type_emb,
                                          emb_ln_g, emb_ln_b, input_ids, token_type, x);

  dim3 g768(HH/64, MM/64);
  dim3 gff(FF/64, MM/64);
  dim3 gattn(LL/64, NH, BB);

  for (int l = 0; l < NL; l++) {
    const float* Wq_l = Wq + (size_t)l*HH*HH;
    const float* Wk_l = Wk + (size_t)l*HH*HH;
    const float* Wv_l = Wv + (size_t)l*HH*HH;
    const float* Wo_l = Wo + (size_t)l*HH*HH;
    const float* W1_l = W1 + (size_t)l*HH*FF;
    const float* W2_l = W2 + (size_t)l*FF*HH;

    gemm_bias<0><<<g768, 256, 0, stream>>>(x, Wq_l, bq + l*HH, qb, MM, HH, HH);
    gemm_bias<0><<<g768, 256, 0, stream>>>(x, Wk_l, bk + l*HH, kb, MM, HH, HH);
    gemm_bias<0><<<g768, 256, 0, stream>>>(x, Wv_l, bv + l*HH, vb, MM, HH, HH);
    attn_kernel<<<gattn, 256, 0, stream>>>(qb, kb, vb, ctxb, seg, vl, bos);
    gemm_bias<0><<<g768, 256, 0, stream>>>(ctxb, Wo_l, bo + l*HH, tmp, MM, HH, HH);
    add_ln_kernel<<<MM, 256, 0, stream>>>(x, tmp, attn_ln_g + l*HH, attn_ln_b + l*HH, x);
    gemm_bias<1><<<gff, 256, 0, stream>>>(x, W1_l, b1 + l*FF, hbuf, MM, FF, HH);
    gemm_bias<0><<<g768, 256, 0, stream>>>(hbuf, W2_l, b2 + l*HH, tmp, MM, HH, FF);
    add_ln_kernel<<<MM, 256, 0, stream>>>(x, tmp, ffn_ln_g + l*HH, ffn_ln_b + l*HH, x);
  }

  rowdot_kernel<<<MM, 256, 0, stream>>>(x, fc_w, rd);
  logits_kernel<<<1, 64, 0, stream>>>(rd, bos, vl, fc_b, out);
}

// Round 2
// 4814.147 us; speedup vs baseline: 1.9056x; 1.9056x over previous
//
#include <hip/hip_runtime.h>
#include <math.h>

#define HH 768
#define FF 3072
#define NL 12
#define NH 12
#define DH 64
#define BB 4
#define LL 512
#define SS 8
#define MM (BB*LL)   // 2048
#define WQSZ (HH*HH)
#define W1SZ (HH*FF)

typedef short bf16x8 __attribute__((ext_vector_type(8)));
typedef float f32x4 __attribute__((ext_vector_type(4)));

__device__ inline ushort f2b(float f) {
  unsigned u = __float_as_uint(f);
  unsigned r = (u + 0x7FFFu + ((u >> 16) & 1u)) >> 16;
  return (ushort)r;
}
__device__ inline float b2f(ushort b) {
  return __uint_as_float(((unsigned)b) << 16);
}

// ---------------- prep: valid_len, seg ids ----------------
__global__ void prep_kernel(const int* __restrict__ am, const int* __restrict__ bos,
                            int* __restrict__ seg, int* __restrict__ vl) {
  int b = blockIdx.x;
  int t = threadIdx.x;            // 512 threads
  __shared__ int red[512];
  red[t] = am[b*LL + t];
  __syncthreads();
  for (int off = 256; off > 0; off >>= 1) {
    if (t < off) red[t] += red[t+off];
    __syncthreads();
  }
  if (t == 0) vl[b] = red[0];
  int cnt = 0;
  #pragma unroll
  for (int s = 0; s < SS; s++) cnt += (bos[b*SS + s] <= t) ? 1 : 0;
  seg[b*LL + t] = cnt - 1;
}

// ---------------- embedding + LayerNorm (writes f32 x and bf16 x) ----------------
__global__ __launch_bounds__(256) void embed_ln_kernel(
    const float* __restrict__ word_emb, const float* __restrict__ pos_emb,
    const float* __restrict__ type_emb, const float* __restrict__ g,
    const float* __restrict__ bta, const int* __restrict__ ids,
    const int* __restrict__ tts, float* __restrict__ x, ushort* __restrict__ xb)
{
  int row = blockIdx.x;           // 0..2047
  int l = row & (LL-1);
  int t = threadIdx.x;
  int id = ids[row];
  int ty = tts[row];
  float v[3];
  float s = 0.f, sq = 0.f;
  #pragma unroll
  for (int j = 0; j < 3; j++) {
    int c = t + j*256;
    float val = word_emb[(size_t)id*HH + c] + pos_emb[l*HH + c] + type_emb[ty*HH + c];
    v[j] = val; s += val; sq += val*val;
  }
  __shared__ float rs[256], rq[256];
  rs[t] = s; rq[t] = sq;
  __syncthreads();
  for (int off = 128; off > 0; off >>= 1) {
    if (t < off) { rs[t] += rs[t+off]; rq[t] += rq[t+off]; }
    __syncthreads();
  }
  float mean = rs[0] / HH;
  float var  = rq[0] / HH - mean*mean;
  float inv  = rsqrtf(var + 1e-12f);
  #pragma unroll
  for (int j = 0; j < 3; j++) {
    int c = t + j*256;
    float o = (v[j]-mean)*inv*g[c] + bta[c];
    x[(size_t)row*HH + c] = o;
    xb[(size_t)row*HH + c] = f2b(o);
  }
}

// ---------------- residual + LayerNorm ----------------
__global__ __launch_bounds__(256) void add_ln_kernel(
    const float* __restrict__ xin, const float* __restrict__ y,
    const float* __restrict__ g, const float* __restrict__ bta,
    float* __restrict__ xout, ushort* __restrict__ xb)
{
  int row = blockIdx.x;
  int t = threadIdx.x;
  float v[3];
  float s = 0.f, sq = 0.f;
  #pragma unroll
  for (int j = 0; j < 3; j++) {
    int c = t + j*256;
    float val = xin[(size_t)row*HH + c] + y[(size_t)row*HH + c];
    v[j] = val; s += val; sq += val*val;
  }
  __shared__ float rs[256], rq[256];
  rs[t] = s; rq[t] = sq;
  __syncthreads();
  for (int off = 128; off > 0; off >>= 1) {
    if (t < off) { rs[t] += rs[t+off]; rq[t] += rq[t+off]; }
    __syncthreads();
  }
  float mean = rs[0] / HH;
  float var  = rq[0] / HH - mean*mean;
  float inv  = rsqrtf(var + 1e-12f);
  #pragma unroll
  for (int j = 0; j < 3; j++) {
    int c = t + j*256;
    float o = (v[j]-mean)*inv*g[c] + bta[c];
    xout[(size_t)row*HH + c] = o;
    xb[(size_t)row*HH + c] = f2b(o);
  }
}

// ---------------- per-layer weight convert + transpose to bf16 ----------------
// wbuf layout: Wq_t, Wk_t, Wv_t, Wo_t (each N x K = 768x768),
//              W1_t (3072 x 768), W2_t (768 x 3072)   [all row-major N x K]
__global__ __launch_bounds__(256) void convw_kernel(
    const float* __restrict__ Wq, const float* __restrict__ Wk,
    const float* __restrict__ Wv, const float* __restrict__ Wo,
    const float* __restrict__ W1, const float* __restrict__ W2,
    ushort* __restrict__ wbuf)
{
  int idx = blockIdx.x;           // 0..1727
  const float* src; ushort* dst; int Nsrc, dstK, kt, nt;
  if (idx < 576) {
    int mat = idx / 144, t = idx % 144;
    src = (mat == 0) ? Wq : (mat == 1) ? Wk : (mat == 2) ? Wv : Wo;
    dst = wbuf + (size_t)mat * WQSZ;
    Nsrc = HH; dstK = HH; kt = t % 12; nt = t / 12;
  } else if (idx < 1152) {
    int t = idx - 576;
    src = W1; dst = wbuf + (size_t)4 * WQSZ;
    Nsrc = FF; dstK = HH; kt = t % 12; nt = t / 12;
  } else {
    int t = idx - 1152;
    src = W2; dst = wbuf + (size_t)4 * WQSZ + W1SZ;
    Nsrc = HH; dstK = FF; kt = t % 48; nt = t / 48;
  }
  int k0 = kt * 64, n0 = nt * 64;
  __shared__ ushort tt[64][72];
  int tid = threadIdx.x;
  int r = tid >> 4, c = (tid & 15) << 2;
  #pragma unroll
  for (int i = 0; i < 4; i++) {
    int rr = r + i*16;
    float4 v = *(const float4*)&src[(size_t)(k0+rr)*Nsrc + n0 + c];
    tt[c+0][rr] = f2b(v.x); tt[c+1][rr] = f2b(v.y);
    tt[c+2][rr] = f2b(v.z); tt[c+3][rr] = f2b(v.w);
  }
  __syncthreads();
  #pragma unroll
  for (int it = 0; it < 2; it++) {
    int n = it*32 + (tid >> 3);
    int k = (tid & 7) << 3;
    ushort tmp8[8];
    #pragma unroll
    for (int j = 0; j < 8; j++) tmp8[j] = tt[n][k+j];
    *(uint4*)&dst[(size_t)(n0+n)*dstK + k0 + k] = *(const uint4*)tmp8;
  }
}

// ---------------- bf16 MFMA GEMM: C = A(MxK,bf16) @ Bt^T + bias ----------------
// Bt is N x K row-major (pre-transposed). 256 threads = 4 waves (2x2).
struct GArg { const ushort* Bt; const float* bias; float* Cf; ushort* Cb; };
struct GArg3 { GArg a[3]; };

template<int BM, int BN, int ACT, int WF32, int WBF16>
__global__ __launch_bounds__(256) void gemm_mfma(
    const ushort* __restrict__ A, GArg3 ga, int M, int N, int K)
{
  constexpr int MFR = BM/32, NFR = BN/32;
  const GArg g = ga.a[blockIdx.z];
  __shared__ __align__(16) ushort As[BM*32];
  __shared__ __align__(16) ushort Bs[BN*32];
  const int tid = threadIdx.x;
  const int lane = tid & 63, wid = tid >> 6;
  const int wm = wid >> 1, wn = wid & 1;
  const int m0 = blockIdx.y * BM, n0 = blockIdx.x * BN;

  f32x4 acc[MFR][NFR] = {};

  for (int k0 = 0; k0 < K; k0 += 32) {
    #pragma unroll
    for (int j = 0; j < BM/64; j++) {
      int cbase = j*256 + wid*64;
      int c = cbase + lane;
      int row = c >> 2, kk = (c & 3) << 3;
      __builtin_amdgcn_global_load_lds(
        (const __attribute__((address_space(1))) void*)(A + (size_t)(m0+row)*K + k0 + kk),
        (__attribute__((address_space(3))) void*)(As + cbase*8), 16, 0, 0);
    }
    #pragma unroll
    for (int j = 0; j < BN/64; j++) {
      int cbase = j*256 + wid*64;
      int c = cbase + lane;
      int row = c >> 2, kk = (c & 3) << 3;
      __builtin_amdgcn_global_load_lds(
        (const __attribute__((address_space(1))) void*)(g.Bt + (size_t)(n0+row)*K + k0 + kk),
        (__attribute__((address_space(3))) void*)(Bs + cbase*8), 16, 0, 0);
    }
    __syncthreads();
    bf16x8 af[MFR], bfr[NFR];
    #pragma unroll
    for (int mi = 0; mi < MFR; mi++) {
      int off = (wm*(BM/2) + mi*16 + (lane&15))*32 + (lane>>4)*8;
      af[mi] = *(const bf16x8*)(As + off);
    }
    #pragma unroll
    for (int ni = 0; ni < NFR; ni++) {
      int off = (wn*(BN/2) + ni*16 + (lane&15))*32 + (lane>>4)*8;
      bfr[ni] = *(const bf16x8*)(Bs + off);
    }
    #pragma unroll
    for (int mi = 0; mi < MFR; mi++)
      #pragma unroll
      for (int ni = 0; ni < NFR; ni++)
        acc[mi][ni] = __builtin_amdgcn_mfma_f32_16x16x32_bf16(af[mi], bfr[ni], acc[mi][ni], 0, 0, 0);
    __syncthreads();
  }

  #pragma unroll
  for (int mi = 0; mi < MFR; mi++) {
    #pragma unroll
    for (int ni = 0; ni < NFR; ni++) {
      int col = n0 + wn*(BN/2) + ni*16 + (lane & 15);
      float bv = g.bias[col];
      #pragma unroll
      for (int r = 0; r < 4; r++) {
        int row = m0 + wm*(BM/2) + mi*16 + (lane >> 4)*4 + r;
        float v = acc[mi][ni][r] + bv;
        if (ACT) v = 0.5f * v * (1.0f + erff(v * 0.70710678118654752f));
        if (WF32)  g.Cf[(size_t)row*N + col] = v;
        if (WBF16) g.Cb[(size_t)row*N + col] = f2b(v);
      }
    }
  }
}

// ---------------- flash attention, f32 math, bf16 Q/K/V in ----------------
__global__ __launch_bounds__(256) void attn_kernel(
    const ushort* __restrict__ Q, const ushort* __restrict__ Kp, const ushort* __restrict__ Vp,
    ushort* __restrict__ ctx, const int* __restrict__ seg, const int* __restrict__ vl,
    const int* __restrict__ bos)
{
  const int q0 = blockIdx.x * 64;
  const int h  = blockIdx.y;
  const int b  = blockIdx.z;
  const int tid = threadIdx.x;

  __shared__ float Qs[64][65];
  __shared__ float Ks[64][65];
  __shared__ float Vs[64][65];
  __shared__ float Sc[64][65];
  __shared__ float mrow[64], lrow[64], srow[64];
  __shared__ int   segk[64];

  // load Q tile (64x64) bf16 -> f32
  #pragma unroll
  for (int it = 0; it < 2; it++) {
    int r = it*32 + (tid >> 3);
    int c8 = (tid & 7) << 3;
    uint4 qv = *(const uint4*)&Q[((size_t)(b*LL + q0 + r))*HH + h*DH + c8];
    unsigned w[4] = {qv.x, qv.y, qv.z, qv.w};
    #pragma unroll
    for (int i = 0; i < 4; i++) {
      Qs[r][c8 + 2*i]     = __uint_as_float(w[i] << 16);
      Qs[r][c8 + 2*i + 1] = __uint_as_float(w[i] & 0xFFFF0000u);
    }
  }
  if (tid < 64) { mrow[tid] = -1e30f; lrow[tid] = 0.f; }

  const int q  = tid & 63;
  const int db = tid >> 6;       // d-block 0..3 (16 cols each)
  const int qg = q0 + q;
  const int vlb = vl[b];
  const int hist = bos[b*SS];
  const int myseg = seg[b*LL + qg];
  const bool qvalid = qg < vlb;

  float o[16];
  #pragma unroll
  for (int j = 0; j < 16; j++) o[j] = 0.f;

  for (int k0 = 0; k0 < LL; k0 += 64) {
    #pragma unroll
    for (int it = 0; it < 2; it++) {
      int r = it*32 + (tid >> 3);
      int c8 = (tid & 7) << 3;
      size_t base = ((size_t)(b*LL + k0 + r))*HH + h*DH + c8;
      uint4 kv = *(const uint4*)&Kp[base];
      unsigned w0[4] = {kv.x, kv.y, kv.z, kv.w};
      #pragma unroll
      for (int i = 0; i < 4; i++) {
        Ks[r][c8 + 2*i]     = __uint_as_float(w0[i] << 16);
        Ks[r][c8 + 2*i + 1] = __uint_as_float(w0[i] & 0xFFFF0000u);
      }
      uint4 vv = *(const uint4*)&Vp[base];
      unsigned w1[4] = {vv.x, vv.y, vv.z, vv.w};
      #pragma unroll
      for (int i = 0; i < 4; i++) {
        Vs[r][c8 + 2*i]     = __uint_as_float(w1[i] << 16);
        Vs[r][c8 + 2*i + 1] = __uint_as_float(w1[i] & 0xFFFF0000u);
      }
    }
    if (tid < 64) segk[tid] = seg[b*LL + k0 + tid];
    __syncthreads();

    #pragma unroll
    for (int jj = 0; jj < 16; jj++) {
      int k = db + (jj << 2);
      float s_ = 0.f;
      #pragma unroll
      for (int d = 0; d < 64; d++) s_ = fmaf(Qs[q][d], Ks[k][d], s_);
      int kg = k0 + k;
      bool kvalid = kg < vlb;
      bool ok = qvalid && kvalid && ((qg < hist) || (kg < hist) || (myseg == segk[k]));
      Sc[q][k] = s_ * 0.125f + (ok ? 0.f : -10000.f);
    }
    __syncthreads();

    if (tid < 64) {
      float mold = mrow[tid];
      float mx = mold;
      for (int k = 0; k < 64; k++) mx = fmaxf(mx, Sc[tid][k]);
      float scl = expf(mold - mx);
      float sum = 0.f;
      for (int k = 0; k < 64; k++) {
        float p = expf(Sc[tid][k] - mx);
        Sc[tid][k] = p;
        sum += p;
      }
      mrow[tid] = mx;
      lrow[tid] = lrow[tid]*scl + sum;
      srow[tid] = scl;
    }
    __syncthreads();

    float scl = srow[q];
    #pragma unroll
    for (int j = 0; j < 16; j++) o[j] *= scl;
    for (int k = 0; k < 64; k++) {
      float p = Sc[q][k];
      #pragma unroll
      for (int j = 0; j < 16; j++)
        o[j] = fmaf(p, Vs[k][(db << 4) + j], o[j]);
    }
    __syncthreads();
  }

  float invl = 1.0f / lrow[q];
  #pragma unroll
  for (int j = 0; j < 16; j++)
    ctx[((size_t)(b*LL + q0 + q))*HH + h*DH + (db << 4) + j] = f2b(o[j] * invl);
}

// ---------------- final pooling ----------------
__global__ __launch_bounds__(256) void rowdot_kernel(const float* __restrict__ x,
                                                     const float* __restrict__ w,
                                                     float* __restrict__ rd) {
  int row = blockIdx.x;
  int t = threadIdx.x;
  float s = 0.f;
  #pragma unroll
  for (int j = 0; j < 3; j++) {
    int c = t + j*256;
    s = fmaf(x[(size_t)row*HH + c], w[c], s);
  }
  __shared__ float red[256];
  red[t] = s;
  __syncthreads();
  for (int off = 128; off > 0; off >>= 1) {
    if (t < off) red[t] += red[t+off];
    __syncthreads();
  }
  if (t == 0) rd[row] = red[0];
}

__global__ void logits_kernel(const float* __restrict__ rd, const int* __restrict__ bos,
                              const int* __restrict__ vl, const float* __restrict__ fcb,
                              float* __restrict__ out) {
  int i = threadIdx.x;
  if (i >= BB*SS) return;
  int b = i / SS, s = i % SS;
  int start = bos[b*SS + s];
  int end   = (s == SS-1) ? vl[b] : bos[b*SS + s + 1];
  float sum = 0.f;
  for (int t = start; t < end; t++) sum += rd[b*LL + t];
  out[i] = sum / (float)(end - start) + fcb[0];
}

extern "C" void kernel_launch(void* const* d_in, const int* in_sizes, int n_in,
                              void* d_out, int out_size, void* d_ws, size_t ws_size,
                              hipStream_t stream) {
  const float* word_emb  = (const float*)d_in[0];
  const float* pos_emb   = (const float*)d_in[1];
  const float* type_emb  = (const float*)d_in[2];
  const float* emb_ln_g  = (const float*)d_in[3];
  const float* emb_ln_b  = (const float*)d_in[4];
  const float* Wq        = (const float*)d_in[5];
  const float* bq        = (const float*)d_in[6];
  const float* Wk        = (const float*)d_in[7];
  const float* bk        = (const float*)d_in[8];
  const float* Wv        = (const float*)d_in[9];
  const float* bv        = (const float*)d_in[10];
  const float* Wo        = (const float*)d_in[11];
  const float* bo        = (const float*)d_in[12];
  const float* attn_ln_g = (const float*)d_in[13];
  const float* attn_ln_b = (const float*)d_in[14];
  const float* W1        = (const float*)d_in[15];
  const float* b1        = (const float*)d_in[16];
  const float* W2        = (const float*)d_in[17];
  const float* b2        = (const float*)d_in[18];
  const float* ffn_ln_g  = (const float*)d_in[19];
  const float* ffn_ln_b  = (const float*)d_in[20];
  const float* fc_w      = (const float*)d_in[21];
  const float* fc_b      = (const float*)d_in[22];
  const int* input_ids   = (const int*)d_in[23];
  const int* token_type  = (const int*)d_in[24];
  const int* am          = (const int*)d_in[25];
  const int* bos         = (const int*)d_in[26];
  float* out = (float*)d_out;

  char* w = (char*)d_ws;
  float*  x       = (float*)w;  w += (size_t)MM*HH*4;
  float*  tmp     = (float*)w;  w += (size_t)MM*HH*4;
  ushort* qkv_bf  = (ushort*)w; w += (size_t)3*MM*HH*2;
  ushort* x_bf    = (ushort*)w; w += (size_t)MM*HH*2;
  ushort* ctx_bf  = (ushort*)w; w += (size_t)MM*HH*2;
  ushort* hbuf_bf = (ushort*)w; w += (size_t)MM*FF*2;
  ushort* wbuf    = (ushort*)w; w += (size_t)(4*WQSZ + 2*W1SZ)*2;
  float*  rd      = (float*)w;  w += (size_t)MM*4;
  int*    seg     = (int*)w;    w += (size_t)MM*4;
  int*    vl      = (int*)w;    w += 64;

  prep_kernel<<<BB, 512, 0, stream>>>(am, bos, seg, vl);
  embed_ln_kernel<<<MM, 256, 0, stream>>>(word_emb, pos_emb, type_emb,
                                          emb_ln_g, emb_ln_b, input_ids, token_type, x, x_bf);

  dim3 gqkv(HH/128, MM/128, 3);
  dim3 g_ff1(FF/128, MM/128, 1);
  dim3 g_n64(HH/64, MM/128, 1);
  dim3 gattn(LL/64, NH, BB);

  for (int l = 0; l < NL; l++) {
    convw_kernel<<<1728, 256, 0, stream>>>(Wq + (size_t)l*WQSZ, Wk + (size_t)l*WQSZ,
                                           Wv + (size_t)l*WQSZ, Wo + (size_t)l*WQSZ,
                                           W1 + (size_t)l*W1SZ, W2 + (size_t)l*W1SZ, wbuf);

    GArg3 gq;
    for (int z = 0; z < 3; z++) {
      gq.a[z].Bt   = wbuf + (size_t)z*WQSZ;
      gq.a[z].bias = (z == 0 ? bq : z == 1 ? bk : bv) + (size_t)l*HH;
      gq.a[z].Cf   = nullptr;
      gq.a[z].Cb   = qkv_bf + (size_t)z*MM*HH;
    }
    gemm_mfma<128,128,0,0,1><<<gqkv, 256, 0, stream>>>(x_bf, gq, MM, HH, HH);

    attn_kernel<<<gattn, 256, 0, stream>>>(qkv_bf, qkv_bf + (size_t)MM*HH,
                                           qkv_bf + (size_t)2*MM*HH, ctx_bf, seg, vl, bos);

    GArg3 go = {};
    go.a[0].Bt = wbuf + (size_t)3*WQSZ; go.a[0].bias = bo + (size_t)l*HH;
    go.a[0].Cf = tmp; go.a[0].Cb = nullptr;
    gemm_mfma<128,64,0,1,0><<<g_n64, 256, 0, stream>>>(ctx_bf, go, MM, HH, HH);

    add_ln_kernel<<<MM, 256, 0, stream>>>(x, tmp, attn_ln_g + (size_t)l*HH,
                                          attn_ln_b + (size_t)l*HH, x, x_bf);

    GArg3 g1 = {};
    g1.a[0].Bt = wbuf + (size_t)4*WQSZ; g1.a[0].bias = b1 + (size_t)l*FF;
    g1.a[0].Cf = nullptr; g1.a[0].Cb = hbuf_bf;
    gemm_mfma<128,128,1,0,1><<<g_ff1, 256, 0, stream>>>(x_bf, g1, MM, FF, HH);

    GArg3 g2 = {};
    g2.a[0].Bt = wbuf + (size_t)4*WQSZ + W1SZ; g2.a[0].bias = b2 + (size_t)l*HH;
    g2.a[0].Cf = tmp; g2.a[0].Cb = nullptr;
    gemm_mfma<128,64,0,1,0><<<g_n64, 256, 0, stream>>>(hbuf_bf, g2, MM, HH, FF);

    add_ln_kernel<<<MM, 256, 0, stream>>>(x, tmp, ffn_ln_g + (size_t)l*HH,
                                          ffn_ln_b + (size_t)l*HH, x, x_bf);
  }

  rowdot_kernel<<<MM, 256, 0, stream>>>(x, fc_w, rd);
  logits_kernel<<<1, 64, 0, stream>>>(rd, bos, vl, fc_b, out);
}

// Round 3
// 1961.148 us; speedup vs baseline: 4.6777x; 2.4548x over previous
//
#include <hip/hip_runtime.h>
#include <math.h>

#define HH 768
#define FF 3072
#define NL 12
#define NH 12
#define DH 64
#define BB 4
#define LL 512
#define SS 8
#define MM (BB*LL)   // 2048
#define WQSZ (HH*HH)
#define W1SZ (HH*FF)

typedef short bf16x8 __attribute__((ext_vector_type(8)));
typedef float f32x4 __attribute__((ext_vector_type(4)));

__device__ inline ushort f2b(float f) {
  unsigned u = __float_as_uint(f);
  unsigned r = (u + 0x7FFFu + ((u >> 16) & 1u)) >> 16;
  return (ushort)r;
}

// ---------------- prep: valid_len, seg ids ----------------
__global__ void prep_kernel(const int* __restrict__ am, const int* __restrict__ bos,
                            int* __restrict__ seg, int* __restrict__ vl) {
  int b = blockIdx.x;
  int t = threadIdx.x;            // 512 threads
  __shared__ int red[512];
  red[t] = am[b*LL + t];
  __syncthreads();
  for (int off = 256; off > 0; off >>= 1) {
    if (t < off) red[t] += red[t+off];
    __syncthreads();
  }
  if (t == 0) vl[b] = red[0];
  int cnt = 0;
  #pragma unroll
  for (int s = 0; s < SS; s++) cnt += (bos[b*SS + s] <= t) ? 1 : 0;
  seg[b*LL + t] = cnt - 1;
}

// ---------------- embedding + LayerNorm (writes f32 x and bf16 x) ----------------
__global__ __launch_bounds__(256) void embed_ln_kernel(
    const float* __restrict__ word_emb, const float* __restrict__ pos_emb,
    const float* __restrict__ type_emb, const float* __restrict__ g,
    const float* __restrict__ bta, const int* __restrict__ ids,
    const int* __restrict__ tts, float* __restrict__ x, ushort* __restrict__ xb)
{
  int row = blockIdx.x;           // 0..2047
  int l = row & (LL-1);
  int t = threadIdx.x;
  int id = ids[row];
  int ty = tts[row];
  float v[3];
  float s = 0.f, sq = 0.f;
  #pragma unroll
  for (int j = 0; j < 3; j++) {
    int c = t + j*256;
    float val = word_emb[(size_t)id*HH + c] + pos_emb[l*HH + c] + type_emb[ty*HH + c];
    v[j] = val; s += val; sq += val*val;
  }
  __shared__ float rs[256], rq[256];
  rs[t] = s; rq[t] = sq;
  __syncthreads();
  for (int off = 128; off > 0; off >>= 1) {
    if (t < off) { rs[t] += rs[t+off]; rq[t] += rq[t+off]; }
    __syncthreads();
  }
  float mean = rs[0] / HH;
  float var  = rq[0] / HH - mean*mean;
  float inv  = rsqrtf(var + 1e-12f);
  #pragma unroll
  for (int j = 0; j < 3; j++) {
    int c = t + j*256;
    float o = (v[j]-mean)*inv*g[c] + bta[c];
    x[(size_t)row*HH + c] = o;
    xb[(size_t)row*HH + c] = f2b(o);
  }
}

// ---------------- residual + LayerNorm ----------------
__global__ __launch_bounds__(256) void add_ln_kernel(
    const float* __restrict__ xin, const float* __restrict__ y,
    const float* __restrict__ g, const float* __restrict__ bta,
    float* __restrict__ xout, ushort* __restrict__ xb)
{
  int row = blockIdx.x;
  int t = threadIdx.x;
  float v[3];
  float s = 0.f, sq = 0.f;
  #pragma unroll
  for (int j = 0; j < 3; j++) {
    int c = t + j*256;
    float val = xin[(size_t)row*HH + c] + y[(size_t)row*HH + c];
    v[j] = val; s += val; sq += val*val;
  }
  __shared__ float rs[256], rq[256];
  rs[t] = s; rq[t] = sq;
  __syncthreads();
  for (int off = 128; off > 0; off >>= 1) {
    if (t < off) { rs[t] += rs[t+off]; rq[t] += rq[t+off]; }
    __syncthreads();
  }
  float mean = rs[0] / HH;
  float var  = rq[0] / HH - mean*mean;
  float inv  = rsqrtf(var + 1e-12f);
  #pragma unroll
  for (int j = 0; j < 3; j++) {
    int c = t + j*256;
    float o = (v[j]-mean)*inv*g[c] + bta[c];
    xout[(size_t)row*HH + c] = o;
    xb[(size_t)row*HH + c] = f2b(o);
  }
}

// ---------------- per-layer weight convert + transpose to bf16 ----------------
__global__ __launch_bounds__(256) void convw_kernel(
    const float* __restrict__ Wq, const float* __restrict__ Wk,
    const float* __restrict__ Wv, const float* __restrict__ Wo,
    const float* __restrict__ W1, const float* __restrict__ W2,
    ushort* __restrict__ wbuf)
{
  int idx = blockIdx.x;           // 0..1727
  const float* src; ushort* dst; int Nsrc, dstK, kt, nt;
  if (idx < 576) {
    int mat = idx / 144, t = idx % 144;
    src = (mat == 0) ? Wq : (mat == 1) ? Wk : (mat == 2) ? Wv : Wo;
    dst = wbuf + (size_t)mat * WQSZ;
    Nsrc = HH; dstK = HH; kt = t % 12; nt = t / 12;
  } else if (idx < 1152) {
    int t = idx - 576;
    src = W1; dst = wbuf + (size_t)4 * WQSZ;
    Nsrc = FF; dstK = HH; kt = t % 12; nt = t / 12;
  } else {
    int t = idx - 1152;
    src = W2; dst = wbuf + (size_t)4 * WQSZ + W1SZ;
    Nsrc = HH; dstK = FF; kt = t % 48; nt = t / 48;
  }
  int k0 = kt * 64, n0 = nt * 64;
  __shared__ ushort tt[64][72];
  int tid = threadIdx.x;
  int r = tid >> 4, c = (tid & 15) << 2;
  #pragma unroll
  for (int i = 0; i < 4; i++) {
    int rr = r + i*16;
    float4 v = *(const float4*)&src[(size_t)(k0+rr)*Nsrc + n0 + c];
    tt[c+0][rr] = f2b(v.x); tt[c+1][rr] = f2b(v.y);
    tt[c+2][rr] = f2b(v.z); tt[c+3][rr] = f2b(v.w);
  }
  __syncthreads();
  #pragma unroll
  for (int it = 0; it < 2; it++) {
    int n = it*32 + (tid >> 3);
    int k = (tid & 7) << 3;
    ushort tmp8[8];
    #pragma unroll
    for (int j = 0; j < 8; j++) tmp8[j] = tt[n][k+j];
    *(uint4*)&dst[(size_t)(n0+n)*dstK + k0 + k] = *(const uint4*)tmp8;
  }
}

// ---------------- bf16 MFMA GEMM: C = A(MxK,bf16) @ Bt^T + bias ----------------
struct GArg { const ushort* Bt; const float* bias; float* Cf; ushort* Cb; };
struct GArg3 { GArg a[3]; };

template<int BM, int BN, int ACT, int WF32, int WBF16>
__global__ __launch_bounds__(256) void gemm_mfma(
    const ushort* __restrict__ A, GArg3 ga, int M, int N, int K)
{
  constexpr int MFR = BM/32, NFR = BN/32;
  const GArg g = ga.a[blockIdx.z];
  __shared__ __align__(16) ushort As[BM*32];
  __shared__ __align__(16) ushort Bs[BN*32];
  const int tid = threadIdx.x;
  const int lane = tid & 63, wid = tid >> 6;
  const int wm = wid >> 1, wn = wid & 1;
  const int m0 = blockIdx.y * BM, n0 = blockIdx.x * BN;

  f32x4 acc[MFR][NFR] = {};

  for (int k0 = 0; k0 < K; k0 += 32) {
    #pragma unroll
    for (int j = 0; j < BM/64; j++) {
      int cbase = j*256 + wid*64;
      int c = cbase + lane;
      int row = c >> 2, kk = (c & 3) << 3;
      __builtin_amdgcn_global_load_lds(
        (const __attribute__((address_space(1))) void*)(A + (size_t)(m0+row)*K + k0 + kk),
        (__attribute__((address_space(3))) void*)(As + cbase*8), 16, 0, 0);
    }
    #pragma unroll
    for (int j = 0; j < BN/64; j++) {
      int cbase = j*256 + wid*64;
      int c = cbase + lane;
      int row = c >> 2, kk = (c & 3) << 3;
      __builtin_amdgcn_global_load_lds(
        (const __attribute__((address_space(1))) void*)(g.Bt + (size_t)(n0+row)*K + k0 + kk),
        (__attribute__((address_space(3))) void*)(Bs + cbase*8), 16, 0, 0);
    }
    __syncthreads();
    bf16x8 af[MFR], bfr[NFR];
    #pragma unroll
    for (int mi = 0; mi < MFR; mi++) {
      int off = (wm*(BM/2) + mi*16 + (lane&15))*32 + (lane>>4)*8;
      af[mi] = *(const bf16x8*)(As + off);
    }
    #pragma unroll
    for (int ni = 0; ni < NFR; ni++) {
      int off = (wn*(BN/2) + ni*16 + (lane&15))*32 + (lane>>4)*8;
      bfr[ni] = *(const bf16x8*)(Bs + off);
    }
    #pragma unroll
    for (int mi = 0; mi < MFR; mi++)
      #pragma unroll
      for (int ni = 0; ni < NFR; ni++)
        acc[mi][ni] = __builtin_amdgcn_mfma_f32_16x16x32_bf16(af[mi], bfr[ni], acc[mi][ni], 0, 0, 0);
    __syncthreads();
  }

  #pragma unroll
  for (int mi = 0; mi < MFR; mi++) {
    #pragma unroll
    for (int ni = 0; ni < NFR; ni++) {
      int col = n0 + wn*(BN/2) + ni*16 + (lane & 15);
      float bv = g.bias[col];
      #pragma unroll
      for (int r = 0; r < 4; r++) {
        int row = m0 + wm*(BM/2) + mi*16 + (lane >> 4)*4 + r;
        float v = acc[mi][ni][r] + bv;
        if (ACT) v = 0.5f * v * (1.0f + erff(v * 0.70710678118654752f));
        if (WF32)  g.Cf[(size_t)row*N + col] = v;
        if (WBF16) g.Cb[(size_t)row*N + col] = f2b(v);
      }
    }
  }
}

// ---------------- MFMA flash attention ----------------
// grid (L/64, NH, B), 256 threads = 4 waves; wave w owns q rows [q0+16w, q0+16w+16).
// K tile [64k][64d] and V^T tile [64d][64k] staged in XOR-swizzled LDS.
__global__ __launch_bounds__(256) void attn_mfma_kernel(
    const ushort* __restrict__ Q, const ushort* __restrict__ Kp, const ushort* __restrict__ Vp,
    ushort* __restrict__ ctx, const int* __restrict__ seg, const int* __restrict__ vl,
    const int* __restrict__ bos)
{
  const int q0 = blockIdx.x * 64;
  const int h  = blockIdx.y;
  const int b  = blockIdx.z;
  const int tid = threadIdx.x;
  const int lane = tid & 63;
  const int wid = tid >> 6;

  __shared__ __align__(16) char Ks[8192];     // [64k][128B] swizzled
  __shared__ __align__(16) char Vt[8192];     // [64d][128B] swizzled (V transposed)
  __shared__ __align__(16) char Ps[4][2048];  // per-wave P [16q][128B] swizzled
  __shared__ int segk[64];

  // Q fragment: A-layout row = lane&15, k-elems (lane>>4)*8..+7 over d
  const int qrow_frag = q0 + wid*16 + (lane & 15);
  bf16x8 qf[2];
  #pragma unroll
  for (int c = 0; c < 2; c++)
    qf[c] = *(const bf16x8*)&Q[((size_t)(b*LL + qrow_frag))*HH + h*DH + 32*c + (lane >> 4)*8];

  const int vlb  = vl[b];
  const int hist = bos[b*SS];
  int segq[4]; bool qvalid[4], qhist[4];
  #pragma unroll
  for (int r = 0; r < 4; r++) {
    int qg = q0 + wid*16 + (lane >> 4)*4 + r;  // C-layout row for this lane
    segq[r]   = seg[b*LL + qg];
    qvalid[r] = qg < vlb;
    qhist[r]  = qg < hist;
  }

  float mrow[4], lrow[4];
  #pragma unroll
  for (int r = 0; r < 4; r++) { mrow[r] = -1e30f; lrow[r] = 0.f; }
  f32x4 Oacc[4] = {};   // 4 d-tiles of 16

  for (int k0 = 0; k0 < LL; k0 += 64) {
    __syncthreads();   // protect K/Vt from previous iteration's readers
    // ---- stage K [64k][64d] (coalesced 16B loads, swizzled b128 writes) ----
    #pragma unroll
    for (int p = 0; p < 2; p++) {
      int r  = (tid >> 3) + 32*p;
      int c8 = (tid & 7) * 8;
      uint4 kv = *(const uint4*)&Kp[((size_t)(b*LL + k0 + r))*HH + h*DH + c8];
      *(uint4*)(Ks + (r*128 + ((c8*2) ^ ((r & 7) << 4)))) = kv;
    }
    // ---- stage V^T [64d][64k] (16B loads, 8x b16 transposed writes, conflict-free) ----
    #pragma unroll
    for (int p = 0; p < 2; p++) {
      int k  = lane;
      int d0 = wid*8 + 32*p;
      uint4 vv = *(const uint4*)&Vp[((size_t)(b*LL + k0 + k))*HH + h*DH + d0];
      const ushort* pv = (const ushort*)&vv;
      #pragma unroll
      for (int j = 0; j < 8; j++) {
        int d = d0 + j;
        *(ushort*)(Vt + (d*128 + ((k*2) ^ ((d & 7) << 4)))) = pv[j];
      }
    }
    if (tid < 64) segk[tid] = seg[b*LL + k0 + tid];
    __syncthreads();

    // ---- S = Q K^T : 4 k-tiles x 2 d-chunks ----
    f32x4 sacc[4] = {};
    #pragma unroll
    for (int t = 0; t < 4; t++) {
      int krow = (lane & 15) + 16*t;
      #pragma unroll
      for (int c = 0; c < 2; c++) {
        bf16x8 kf = *(const bf16x8*)(Ks + (krow*128 +
                      (((32*c + (lane >> 4)*8)*2) ^ ((krow & 7) << 4))));
        sacc[t] = __builtin_amdgcn_mfma_f32_16x16x32_bf16(qf[c], kf, sacc[t], 0, 0, 0);
      }
    }

    // ---- scale + mask ----
    #pragma unroll
    for (int t = 0; t < 4; t++) {
      int kg = k0 + (lane & 15) + 16*t;
      bool kvalid = kg < vlb;
      bool khist  = kg < hist;
      int  sk     = segk[(lane & 15) + 16*t];
      #pragma unroll
      for (int r = 0; r < 4; r++) {
        bool ok = qvalid[r] && kvalid && (khist || qhist[r] || (segq[r] == sk));
        sacc[t][r] = sacc[t][r]*0.125f + (ok ? 0.f : -10000.f);
      }
    }

    // ---- online softmax (wave-parallel, 16-lane k-group reduce) ----
    float scl[4];
    #pragma unroll
    for (int r = 0; r < 4; r++) {
      float rm = fmaxf(fmaxf(sacc[0][r], sacc[1][r]), fmaxf(sacc[2][r], sacc[3][r]));
      rm = fmaxf(rm, __shfl_xor(rm, 1));
      rm = fmaxf(rm, __shfl_xor(rm, 2));
      rm = fmaxf(rm, __shfl_xor(rm, 4));
      rm = fmaxf(rm, __shfl_xor(rm, 8));
      float mnew = fmaxf(mrow[r], rm);
      scl[r] = __expf(mrow[r] - mnew);
      float rsum = 0.f;
      #pragma unroll
      for (int t = 0; t < 4; t++) {
        float p = __expf(sacc[t][r] - mnew);
        sacc[t][r] = p;
        rsum += p;
      }
      rsum += __shfl_xor(rsum, 1);
      rsum += __shfl_xor(rsum, 2);
      rsum += __shfl_xor(rsum, 4);
      rsum += __shfl_xor(rsum, 8);
      mrow[r] = mnew;
      lrow[r] = lrow[r]*scl[r] + rsum;
    }

    // ---- P (C-layout) -> bf16 -> per-wave LDS -> A-layout fragments ----
    char* Pl = Ps[wid];
    #pragma unroll
    for (int t = 0; t < 4; t++) {
      #pragma unroll
      for (int r = 0; r < 4; r++) {
        int q = (lane >> 4)*4 + r;
        int k = (lane & 15) + 16*t;
        *(ushort*)(Pl + (q*128 + ((k*2) ^ ((q & 7) << 4)))) = f2b(sacc[t][r]);
      }
    }
    asm volatile("s_waitcnt lgkmcnt(0)" ::: "memory");  // wave-local write->read fence
    bf16x8 pf[2];
    #pragma unroll
    for (int c = 0; c < 2; c++) {
      int q = lane & 15;
      int k = 32*c + (lane >> 4)*8;
      pf[c] = *(const bf16x8*)(Pl + (q*128 + ((k*2) ^ ((q & 7) << 4))));
    }

    // ---- O = O*scl + P V ----
    #pragma unroll
    for (int nt = 0; nt < 4; nt++) {
      #pragma unroll
      for (int r = 0; r < 4; r++) Oacc[nt][r] *= scl[r];
      int d = (lane & 15) + 16*nt;
      #pragma unroll
      for (int c = 0; c < 2; c++) {
        int k = 32*c + (lane >> 4)*8;
        bf16x8 vf = *(const bf16x8*)(Vt + (d*128 + ((k*2) ^ ((d & 7) << 4))));
        Oacc[nt] = __builtin_amdgcn_mfma_f32_16x16x32_bf16(pf[c], vf, Oacc[nt], 0, 0, 0);
      }
    }
  }

  // ---- epilogue ----
  #pragma unroll
  for (int nt = 0; nt < 4; nt++) {
    #pragma unroll
    for (int r = 0; r < 4; r++) {
      int q = q0 + wid*16 + (lane >> 4)*4 + r;
      int d = h*DH + (lane & 15) + 16*nt;
      ctx[(size_t)(b*LL + q)*HH + d] = f2b(Oacc[nt][r] / lrow[r]);
    }
  }
}

// ---------------- final pooling ----------------
__global__ __launch_bounds__(256) void rowdot_kernel(const float* __restrict__ x,
                                                     const float* __restrict__ w,
                                                     float* __restrict__ rd) {
  int row = blockIdx.x;
  int t = threadIdx.x;
  float s = 0.f;
  #pragma unroll
  for (int j = 0; j < 3; j++) {
    int c = t + j*256;
    s = fmaf(x[(size_t)row*HH + c], w[c], s);
  }
  __shared__ float red[256];
  red[t] = s;
  __syncthreads();
  for (int off = 128; off > 0; off >>= 1) {
    if (t < off) red[t] += red[t+off];
    __syncthreads();
  }
  if (t == 0) rd[row] = red[0];
}

__global__ void logits_kernel(const float* __restrict__ rd, const int* __restrict__ bos,
                              const int* __restrict__ vl, const float* __restrict__ fcb,
                              float* __restrict__ out) {
  int i = threadIdx.x;
  if (i >= BB*SS) return;
  int b = i / SS, s = i % SS;
  int start = bos[b*SS + s];
  int end   = (s == SS-1) ? vl[b] : bos[b*SS + s + 1];
  float sum = 0.f;
  for (int t = start; t < end; t++) sum += rd[b*LL + t];
  out[i] = sum / (float)(end - start) + fcb[0];
}

extern "C" void kernel_launch(void* const* d_in, const int* in_sizes, int n_in,
                              void* d_out, int out_size, void* d_ws, size_t ws_size,
                              hipStream_t stream) {
  const float* word_emb  = (const float*)d_in[0];
  const float* pos_emb   = (const float*)d_in[1];
  const float* type_emb  = (const float*)d_in[2];
  const float* emb_ln_g  = (const float*)d_in[3];
  const float* emb_ln_b  = (const float*)d_in[4];
  const float* Wq        = (const float*)d_in[5];
  const float* bq        = (const float*)d_in[6];
  const float* Wk        = (const float*)d_in[7];
  const float* bk        = (const float*)d_in[8];
  const float* Wv        = (const float*)d_in[9];
  const float* bv        = (const float*)d_in[10];
  const float* Wo        = (const float*)d_in[11];
  const float* bo        = (const float*)d_in[12];
  const float* attn_ln_g = (const float*)d_in[13];
  const float* attn_ln_b = (const float*)d_in[14];
  const float* W1        = (const float*)d_in[15];
  const float* b1        = (const float*)d_in[16];
  const float* W2        = (const float*)d_in[17];
  const float* b2        = (const float*)d_in[18];
  const float* ffn_ln_g  = (const float*)d_in[19];
  const float* ffn_ln_b  = (const float*)d_in[20];
  const float* fc_w      = (const float*)d_in[21];
  const float* fc_b      = (const float*)d_in[22];
  const int* input_ids   = (const int*)d_in[23];
  const int* token_type  = (const int*)d_in[24];
  const int* am          = (const int*)d_in[25];
  const int* bos         = (const int*)d_in[26];
  float* out = (float*)d_out;

  char* w = (char*)d_ws;
  float*  x       = (float*)w;  w += (size_t)MM*HH*4;
  float*  tmp     = (float*)w;  w += (size_t)MM*HH*4;
  ushort* qkv_bf  = (ushort*)w; w += (size_t)3*MM*HH*2;
  ushort* x_bf    = (ushort*)w; w += (size_t)MM*HH*2;
  ushort* ctx_bf  = (ushort*)w; w += (size_t)MM*HH*2;
  ushort* hbuf_bf = (ushort*)w; w += (size_t)MM*FF*2;
  ushort* wbuf    = (ushort*)w; w += (size_t)(4*WQSZ + 2*W1SZ)*2;
  float*  rd      = (float*)w;  w += (size_t)MM*4;
  int*    seg     = (int*)w;    w += (size_t)MM*4;
  int*    vl      = (int*)w;    w += 64;

  prep_kernel<<<BB, 512, 0, stream>>>(am, bos, seg, vl);
  embed_ln_kernel<<<MM, 256, 0, stream>>>(word_emb, pos_emb, type_emb,
                                          emb_ln_g, emb_ln_b, input_ids, token_type, x, x_bf);

  dim3 gqkv(HH/128, MM/128, 3);
  dim3 g_ff1(FF/128, MM/128, 1);
  dim3 g_n64(HH/64, MM/128, 1);
  dim3 gattn(LL/64, NH, BB);

  for (int l = 0; l < NL; l++) {
    convw_kernel<<<1728, 256, 0, stream>>>(Wq + (size_t)l*WQSZ, Wk + (size_t)l*WQSZ,
                                           Wv + (size_t)l*WQSZ, Wo + (size_t)l*WQSZ,
                                           W1 + (size_t)l*W1SZ, W2 + (size_t)l*W1SZ, wbuf);

    GArg3 gq;
    for (int z = 0; z < 3; z++) {
      gq.a[z].Bt   = wbuf + (size_t)z*WQSZ;
      gq.a[z].bias = (z == 0 ? bq : z == 1 ? bk : bv) + (size_t)l*HH;
      gq.a[z].Cf   = nullptr;
      gq.a[z].Cb   = qkv_bf + (size_t)z*MM*HH;
    }
    gemm_mfma<128,128,0,0,1><<<gqkv, 256, 0, stream>>>(x_bf, gq, MM, HH, HH);

    attn_mfma_kernel<<<gattn, 256, 0, stream>>>(qkv_bf, qkv_bf + (size_t)MM*HH,
                                                qkv_bf + (size_t)2*MM*HH, ctx_bf, seg, vl, bos);

    GArg3 go = {};
    go.a[0].Bt = wbuf + (size_t)3*WQSZ; go.a[0].bias = bo + (size_t)l*HH;
    go.a[0].Cf = tmp; go.a[0].Cb = nullptr;
    gemm_mfma<128,64,0,1,0><<<g_n64, 256, 0, stream>>>(ctx_bf, go, MM, HH, HH);

    add_ln_kernel<<<MM, 256, 0, stream>>>(x, tmp, attn_ln_g + (size_t)l*HH,
                                          attn_ln_b + (size_t)l*HH, x, x_bf);

    GArg3 g1 = {};
    g1.a[0].Bt = wbuf + (size_t)4*WQSZ; g1.a[0].bias = b1 + (size_t)l*FF;
    g1.a[0].Cf = nullptr; g1.a[0].Cb = hbuf_bf;
    gemm_mfma<128,128,1,0,1><<<g_ff1, 256, 0, stream>>>(x_bf, g1, MM, FF, HH);

    GArg3 g2 = {};
    g2.a[0].Bt = wbuf + (size_t)4*WQSZ + W1SZ; g2.a[0].bias = b2 + (size_t)l*HH;
    g2.a[0].Cf = tmp; g2.a[0].Cb = nullptr;
    gemm_mfma<128,64,0,1,0><<<g_n64, 256, 0, stream>>>(hbuf_bf, g2, MM, HH, FF);

    add_ln_kernel<<<MM, 256, 0, stream>>>(x, tmp, ffn_ln_g + (size_t)l*HH,
                                          ffn_ln_b + (size_t)l*HH, x, x_bf);
  }

  rowdot_kernel<<<MM, 256, 0, stream>>>(x, fc_w, rd);
  logits_kernel<<<1, 64, 0, stream>>>(rd, bos, vl, fc_b, out);
}

// Round 4
// 1456.263 us; speedup vs baseline: 6.2995x; 1.3467x over previous
//
#include <hip/hip_runtime.h>
#include <math.h>

#define HH 768
#define FF 3072
#define NL 12
#define NH 12
#define DH 64
#define BB 4
#define LL 512
#define SS 8
#define MM (BB*LL)   // 2048
#define WQSZ (HH*HH)
#define W1SZ (HH*FF)

typedef short bf16x8 __attribute__((ext_vector_type(8)));
typedef float f32x4 __attribute__((ext_vector_type(4)));

__device__ inline ushort f2b(float f) {
  unsigned u = __float_as_uint(f);
  unsigned r = (u + 0x7FFFu + ((u >> 16) & 1u)) >> 16;
  return (ushort)r;
}

// ---------------- prep: valid_len, seg ids ----------------
__global__ void prep_kernel(const int* __restrict__ am, const int* __restrict__ bos,
                            int* __restrict__ seg, int* __restrict__ vl) {
  int b = blockIdx.x;
  int t = threadIdx.x;            // 512 threads
  __shared__ int red[512];
  red[t] = am[b*LL + t];
  __syncthreads();
  for (int off = 256; off > 0; off >>= 1) {
    if (t < off) red[t] += red[t+off];
    __syncthreads();
  }
  if (t == 0) vl[b] = red[0];
  int cnt = 0;
  #pragma unroll
  for (int s = 0; s < SS; s++) cnt += (bos[b*SS + s] <= t) ? 1 : 0;
  seg[b*LL + t] = cnt - 1;
}

// ---------------- embedding + LayerNorm (writes f32 x and bf16 x) ----------------
__global__ __launch_bounds__(256) void embed_ln_kernel(
    const float* __restrict__ word_emb, const float* __restrict__ pos_emb,
    const float* __restrict__ type_emb, const float* __restrict__ g,
    const float* __restrict__ bta, const int* __restrict__ ids,
    const int* __restrict__ tts, float* __restrict__ x, ushort* __restrict__ xb)
{
  int row = blockIdx.x;           // 0..2047
  int l = row & (LL-1);
  int t = threadIdx.x;
  int id = ids[row];
  int ty = tts[row];
  float v[3];
  float s = 0.f, sq = 0.f;
  #pragma unroll
  for (int j = 0; j < 3; j++) {
    int c = t + j*256;
    float val = word_emb[(size_t)id*HH + c] + pos_emb[l*HH + c] + type_emb[ty*HH + c];
    v[j] = val; s += val; sq += val*val;
  }
  __shared__ float rs[256], rq[256];
  rs[t] = s; rq[t] = sq;
  __syncthreads();
  for (int off = 128; off > 0; off >>= 1) {
    if (t < off) { rs[t] += rs[t+off]; rq[t] += rq[t+off]; }
    __syncthreads();
  }
  float mean = rs[0] / HH;
  float var  = rq[0] / HH - mean*mean;
  float inv  = rsqrtf(var + 1e-12f);
  #pragma unroll
  for (int j = 0; j < 3; j++) {
    int c = t + j*256;
    float o = (v[j]-mean)*inv*g[c] + bta[c];
    x[(size_t)row*HH + c] = o;
    xb[(size_t)row*HH + c] = f2b(o);
  }
}

// ---------------- residual + 2 partials + LayerNorm ----------------
__global__ __launch_bounds__(256) void add_ln2_kernel(
    const float* __restrict__ xin, const float* __restrict__ y1,
    const float* __restrict__ y2, const float* __restrict__ g,
    const float* __restrict__ bta, float* __restrict__ xout, ushort* __restrict__ xb)
{
  int row = blockIdx.x;
  int t = threadIdx.x;
  float v[3];
  float s = 0.f, sq = 0.f;
  #pragma unroll
  for (int j = 0; j < 3; j++) {
    int c = t + j*256;
    size_t ix = (size_t)row*HH + c;
    float val = xin[ix] + y1[ix] + y2[ix];
    v[j] = val; s += val; sq += val*val;
  }
  __shared__ float rs[256], rq[256];
  rs[t] = s; rq[t] = sq;
  __syncthreads();
  for (int off = 128; off > 0; off >>= 1) {
    if (t < off) { rs[t] += rs[t+off]; rq[t] += rq[t+off]; }
    __syncthreads();
  }
  float mean = rs[0] / HH;
  float var  = rq[0] / HH - mean*mean;
  float inv  = rsqrtf(var + 1e-12f);
  #pragma unroll
  for (int j = 0; j < 3; j++) {
    int c = t + j*256;
    float o = (v[j]-mean)*inv*g[c] + bta[c];
    xout[(size_t)row*HH + c] = o;
    xb[(size_t)row*HH + c] = f2b(o);
  }
}

// ---------------- per-layer weight convert + transpose to bf16 ----------------
__global__ __launch_bounds__(256) void convw_kernel(
    const float* __restrict__ Wq, const float* __restrict__ Wk,
    const float* __restrict__ Wv, const float* __restrict__ Wo,
    const float* __restrict__ W1, const float* __restrict__ W2,
    ushort* __restrict__ wbuf)
{
  int idx = blockIdx.x;           // 0..1727
  const float* src; ushort* dst; int Nsrc, dstK, kt, nt;
  if (idx < 576) {
    int mat = idx / 144, t = idx % 144;
    src = (mat == 0) ? Wq : (mat == 1) ? Wk : (mat == 2) ? Wv : Wo;
    dst = wbuf + (size_t)mat * WQSZ;
    Nsrc = HH; dstK = HH; kt = t % 12; nt = t / 12;
  } else if (idx < 1152) {
    int t = idx - 576;
    src = W1; dst = wbuf + (size_t)4 * WQSZ;
    Nsrc = FF; dstK = HH; kt = t % 12; nt = t / 12;
  } else {
    int t = idx - 1152;
    src = W2; dst = wbuf + (size_t)4 * WQSZ + W1SZ;
    Nsrc = HH; dstK = FF; kt = t % 48; nt = t / 48;
  }
  int k0 = kt * 64, n0 = nt * 64;
  __shared__ ushort tt[64][72];
  int tid = threadIdx.x;
  int r = tid >> 4, c = (tid & 15) << 2;
  #pragma unroll
  for (int i = 0; i < 4; i++) {
    int rr = r + i*16;
    float4 v = *(const float4*)&src[(size_t)(k0+rr)*Nsrc + n0 + c];
    tt[c+0][rr] = f2b(v.x); tt[c+1][rr] = f2b(v.y);
    tt[c+2][rr] = f2b(v.z); tt[c+3][rr] = f2b(v.w);
  }
  __syncthreads();
  #pragma unroll
  for (int it = 0; it < 2; it++) {
    int n = it*32 + (tid >> 3);
    int k = (tid & 7) << 3;
    ushort tmp8[8];
    #pragma unroll
    for (int j = 0; j < 8; j++) tmp8[j] = tt[n][k+j];
    *(uint4*)&dst[(size_t)(n0+n)*dstK + k0 + k] = *(const uint4*)tmp8;
  }
}

// ---------------- bf16 MFMA GEMM, 64x64 tile, BK=64, 2-phase prefetch ----------------
// Bt is N x K row-major. 256 threads = 4 waves (2x2 quadrants of 32x32).
// LDS XOR-swizzled (chunk ^= row&7) via pre-swizzled global source.
struct GArg { const ushort* Bt; const float* bias; float* Cf; ushort* Cb; };
struct GArg3 { GArg a[3]; };

template<int ACT, int WF32, int WBF16, int SPLITK>
__global__ __launch_bounds__(256) void gemm_mfma64(
    const ushort* __restrict__ A, GArg3 ga, int M, int N, int K)
{
  const GArg g = SPLITK ? ga.a[0] : ga.a[blockIdx.z];
  __shared__ __align__(16) ushort As[2][64*64];
  __shared__ __align__(16) ushort Bs[2][64*64];
  const int tid = threadIdx.x;
  const int lane = tid & 63, wid = tid >> 6;
  const int wm = wid >> 1, wn = wid & 1;
  const int m0 = blockIdx.y * 64, n0 = blockIdx.x * 64;
  int kbeg = 0, kend = K;
  if (SPLITK) { int kh = K >> 1; kbeg = blockIdx.z * kh; kend = kbeg + kh; }

  auto STAGE = [&](int buf, int k0) {
    #pragma unroll
    for (int j = 0; j < 2; j++) {
      int cbase = j*256 + wid*64;
      int c = cbase + lane;
      int r = c >> 3;
      int kk = ((c & 7) ^ (r & 7)) << 3;
      __builtin_amdgcn_global_load_lds(
        (const __attribute__((address_space(1))) void*)(A + (size_t)(m0+r)*K + k0 + kk),
        (__attribute__((address_space(3))) void*)(&As[buf][cbase*8]), 16, 0, 0);
    }
    #pragma unroll
    for (int j = 0; j < 2; j++) {
      int cbase = j*256 + wid*64;
      int c = cbase + lane;
      int r = c >> 3;
      int kk = ((c & 7) ^ (r & 7)) << 3;
      __builtin_amdgcn_global_load_lds(
        (const __attribute__((address_space(1))) void*)(g.Bt + (size_t)(n0+r)*K + k0 + kk),
        (__attribute__((address_space(3))) void*)(&Bs[buf][cbase*8]), 16, 0, 0);
    }
  };

  f32x4 acc[2][2] = {};
  const int NT = (kend - kbeg) >> 6;
  STAGE(0, kbeg);
  __syncthreads();
  int cur = 0;
  for (int t = 0; t < NT; ++t) {
    if (t + 1 < NT) STAGE(cur ^ 1, kbeg + (t+1)*64);
    bf16x8 af[2][2], bfv[2][2];
    #pragma unroll
    for (int mi = 0; mi < 2; mi++) {
      int row = wm*32 + mi*16 + (lane & 15);
      #pragma unroll
      for (int ks = 0; ks < 2; ks++) {
        int kb = (ks*64 + ((lane >> 4) << 4)) ^ ((row & 7) << 4);
        af[mi][ks] = *(const bf16x8*)((const char*)&As[cur][0] + row*128 + kb);
      }
    }
    #pragma unroll
    for (int ni = 0; ni < 2; ni++) {
      int row = wn*32 + ni*16 + (lane & 15);
      #pragma unroll
      for (int ks = 0; ks < 2; ks++) {
        int kb = (ks*64 + ((lane >> 4) << 4)) ^ ((row & 7) << 4);
        bfv[ni][ks] = *(const bf16x8*)((const char*)&Bs[cur][0] + row*128 + kb);
      }
    }
    #pragma unroll
    for (int ks = 0; ks < 2; ks++)
      #pragma unroll
      for (int mi = 0; mi < 2; mi++)
        #pragma unroll
        for (int ni = 0; ni < 2; ni++)
          acc[mi][ni] = __builtin_amdgcn_mfma_f32_16x16x32_bf16(af[mi][ks], bfv[ni][ks], acc[mi][ni], 0, 0, 0);
    __syncthreads();
    cur ^= 1;
  }

  #pragma unroll
  for (int mi = 0; mi < 2; mi++) {
    #pragma unroll
    for (int ni = 0; ni < 2; ni++) {
      int col = n0 + wn*32 + ni*16 + (lane & 15);
      float bv = (!SPLITK || blockIdx.z == 0) ? g.bias[col] : 0.f;
      #pragma unroll
      for (int r = 0; r < 4; r++) {
        int row = m0 + wm*32 + mi*16 + (lane >> 4)*4 + r;
        float v = acc[mi][ni][r] + bv;
        if (ACT) v = 0.5f * v * (1.0f + erff(v * 0.70710678118654752f));
        if (WF32)  g.Cf[(SPLITK ? (size_t)blockIdx.z*M*N : 0) + (size_t)row*N + col] = v;
        if (WBF16) g.Cb[(size_t)row*N + col] = f2b(v);
      }
    }
  }
}

// ---------------- MFMA flash attention ----------------
__global__ __launch_bounds__(256) void attn_mfma_kernel(
    const ushort* __restrict__ Q, const ushort* __restrict__ Kp, const ushort* __restrict__ Vp,
    ushort* __restrict__ ctx, const int* __restrict__ seg, const int* __restrict__ vl,
    const int* __restrict__ bos)
{
  const int q0 = blockIdx.x * 64;
  const int h  = blockIdx.y;
  const int b  = blockIdx.z;
  const int tid = threadIdx.x;
  const int lane = tid & 63;
  const int wid = tid >> 6;

  __shared__ __align__(16) char Ks[8192];     // [64k][128B] swizzled
  __shared__ __align__(16) char Vt[8192];     // [64d][128B] swizzled (V transposed)
  __shared__ __align__(16) char Ps[4][2048];  // per-wave P [16q][128B] swizzled
  __shared__ int segk[64];

  const int qrow_frag = q0 + wid*16 + (lane & 15);
  bf16x8 qf[2];
  #pragma unroll
  for (int c = 0; c < 2; c++)
    qf[c] = *(const bf16x8*)&Q[((size_t)(b*LL + qrow_frag))*HH + h*DH + 32*c + (lane >> 4)*8];

  const int vlb  = vl[b];
  const int hist = bos[b*SS];
  int segq[4]; bool qvalid[4], qhist[4];
  #pragma unroll
  for (int r = 0; r < 4; r++) {
    int qg = q0 + wid*16 + (lane >> 4)*4 + r;
    segq[r]   = seg[b*LL + qg];
    qvalid[r] = qg < vlb;
    qhist[r]  = qg < hist;
  }

  float mrow[4], lrow[4];
  #pragma unroll
  for (int r = 0; r < 4; r++) { mrow[r] = -1e30f; lrow[r] = 0.f; }
  f32x4 Oacc[4] = {};

  for (int k0 = 0; k0 < LL; k0 += 64) {
    __syncthreads();
    #pragma unroll
    for (int p = 0; p < 2; p++) {
      int r  = (tid >> 3) + 32*p;
      int c8 = (tid & 7) * 8;
      uint4 kv = *(const uint4*)&Kp[((size_t)(b*LL + k0 + r))*HH + h*DH + c8];
      *(uint4*)(Ks + (r*128 + ((c8*2) ^ ((r & 7) << 4)))) = kv;
    }
    #pragma unroll
    for (int p = 0; p < 2; p++) {
      int k  = lane;
      int d0 = wid*8 + 32*p;
      uint4 vv = *(const uint4*)&Vp[((size_t)(b*LL + k0 + k))*HH + h*DH + d0];
      const ushort* pv = (const ushort*)&vv;
      #pragma unroll
      for (int j = 0; j < 8; j++) {
        int d = d0 + j;
        *(ushort*)(Vt + (d*128 + ((k*2) ^ ((d & 7) << 4)))) = pv[j];
      }
    }
    if (tid < 64) segk[tid] = seg[b*LL + k0 + tid];
    __syncthreads();

    f32x4 sacc[4] = {};
    #pragma unroll
    for (int t = 0; t < 4; t++) {
      int krow = (lane & 15) + 16*t;
      #pragma unroll
      for (int c = 0; c < 2; c++) {
        bf16x8 kf = *(const bf16x8*)(Ks + (krow*128 +
                      (((32*c + (lane >> 4)*8)*2) ^ ((krow & 7) << 4))));
        sacc[t] = __builtin_amdgcn_mfma_f32_16x16x32_bf16(qf[c], kf, sacc[t], 0, 0, 0);
      }
    }

    #pragma unroll
    for (int t = 0; t < 4; t++) {
      int kg = k0 + (lane & 15) + 16*t;
      bool kvalid = kg < vlb;
      bool khist  = kg < hist;
      int  sk     = segk[(lane & 15) + 16*t];
      #pragma unroll
      for (int r = 0; r < 4; r++) {
        bool ok = qvalid[r] && kvalid && (khist || qhist[r] || (segq[r] == sk));
        sacc[t][r] = sacc[t][r]*0.125f + (ok ? 0.f : -10000.f);
      }
    }

    float scl[4];
    #pragma unroll
    for (int r = 0; r < 4; r++) {
      float rm = fmaxf(fmaxf(sacc[0][r], sacc[1][r]), fmaxf(sacc[2][r], sacc[3][r]));
      rm = fmaxf(rm, __shfl_xor(rm, 1));
      rm = fmaxf(rm, __shfl_xor(rm, 2));
      rm = fmaxf(rm, __shfl_xor(rm, 4));
      rm = fmaxf(rm, __shfl_xor(rm, 8));
      float mnew = fmaxf(mrow[r], rm);
      scl[r] = __expf(mrow[r] - mnew);
      float rsum = 0.f;
      #pragma unroll
      for (int t = 0; t < 4; t++) {
        float p = __expf(sacc[t][r] - mnew);
        sacc[t][r] = p;
        rsum += p;
      }
      rsum += __shfl_xor(rsum, 1);
      rsum += __shfl_xor(rsum, 2);
      rsum += __shfl_xor(rsum, 4);
      rsum += __shfl_xor(rsum, 8);
      mrow[r] = mnew;
      lrow[r] = lrow[r]*scl[r] + rsum;
    }

    char* Pl = Ps[wid];
    #pragma unroll
    for (int t = 0; t < 4; t++) {
      #pragma unroll
      for (int r = 0; r < 4; r++) {
        int q = (lane >> 4)*4 + r;
        int k = (lane & 15) + 16*t;
        *(ushort*)(Pl + (q*128 + ((k*2) ^ ((q & 7) << 4)))) = f2b(sacc[t][r]);
      }
    }
    asm volatile("s_waitcnt lgkmcnt(0)" ::: "memory");
    bf16x8 pf[2];
    #pragma unroll
    for (int c = 0; c < 2; c++) {
      int q = lane & 15;
      int k = 32*c + (lane >> 4)*8;
      pf[c] = *(const bf16x8*)(Pl + (q*128 + ((k*2) ^ ((q & 7) << 4))));
    }

    #pragma unroll
    for (int nt = 0; nt < 4; nt++) {
      #pragma unroll
      for (int r = 0; r < 4; r++) Oacc[nt][r] *= scl[r];
      int d = (lane & 15) + 16*nt;
      #pragma unroll
      for (int c = 0; c < 2; c++) {
        int k = 32*c + (lane >> 4)*8;
        bf16x8 vf = *(const bf16x8*)(Vt + (d*128 + ((k*2) ^ ((d & 7) << 4))));
        Oacc[nt] = __builtin_amdgcn_mfma_f32_16x16x32_bf16(pf[c], vf, Oacc[nt], 0, 0, 0);
      }
    }
  }

  #pragma unroll
  for (int nt = 0; nt < 4; nt++) {
    #pragma unroll
    for (int r = 0; r < 4; r++) {
      int q = q0 + wid*16 + (lane >> 4)*4 + r;
      int d = h*DH + (lane & 15) + 16*nt;
      ctx[(size_t)(b*LL + q)*HH + d] = f2b(Oacc[nt][r] / lrow[r]);
    }
  }
}

// ---------------- final pooling ----------------
__global__ __launch_bounds__(256) void rowdot_kernel(const float* __restrict__ x,
                                                     const float* __restrict__ w,
                                                     float* __restrict__ rd) {
  int row = blockIdx.x;
  int t = threadIdx.x;
  float s = 0.f;
  #pragma unroll
  for (int j = 0; j < 3; j++) {
    int c = t + j*256;
    s = fmaf(x[(size_t)row*HH + c], w[c], s);
  }
  __shared__ float red[256];
  red[t] = s;
  __syncthreads();
  for (int off = 128; off > 0; off >>= 1) {
    if (t < off) red[t] += red[t+off];
    __syncthreads();
  }
  if (t == 0) rd[row] = red[0];
}

__global__ void logits_kernel(const float* __restrict__ rd, const int* __restrict__ bos,
                              const int* __restrict__ vl, const float* __restrict__ fcb,
                              float* __restrict__ out) {
  int i = threadIdx.x;
  if (i >= BB*SS) return;
  int b = i / SS, s = i % SS;
  int start = bos[b*SS + s];
  int end   = (s == SS-1) ? vl[b] : bos[b*SS + s + 1];
  float sum = 0.f;
  for (int t = start; t < end; t++) sum += rd[b*LL + t];
  out[i] = sum / (float)(end - start) + fcb[0];
}

extern "C" void kernel_launch(void* const* d_in, const int* in_sizes, int n_in,
                              void* d_out, int out_size, void* d_ws, size_t ws_size,
                              hipStream_t stream) {
  const float* word_emb  = (const float*)d_in[0];
  const float* pos_emb   = (const float*)d_in[1];
  const float* type_emb  = (const float*)d_in[2];
  const float* emb_ln_g  = (const float*)d_in[3];
  const float* emb_ln_b  = (const float*)d_in[4];
  const float* Wq        = (const float*)d_in[5];
  const float* bq        = (const float*)d_in[6];
  const float* Wk        = (const float*)d_in[7];
  const float* bk        = (const float*)d_in[8];
  const float* Wv        = (const float*)d_in[9];
  const float* bv        = (const float*)d_in[10];
  const float* Wo        = (const float*)d_in[11];
  const float* bo        = (const float*)d_in[12];
  const float* attn_ln_g = (const float*)d_in[13];
  const float* attn_ln_b = (const float*)d_in[14];
  const float* W1        = (const float*)d_in[15];
  const float* b1        = (const float*)d_in[16];
  const float* W2        = (const float*)d_in[17];
  const float* b2        = (const float*)d_in[18];
  const float* ffn_ln_g  = (const float*)d_in[19];
  const float* ffn_ln_b  = (const float*)d_in[20];
  const float* fc_w      = (const float*)d_in[21];
  const float* fc_b      = (const float*)d_in[22];
  const int* input_ids   = (const int*)d_in[23];
  const int* token_type  = (const int*)d_in[24];
  const int* am          = (const int*)d_in[25];
  const int* bos         = (const int*)d_in[26];
  float* out = (float*)d_out;

  char* w = (char*)d_ws;
  float*  x       = (float*)w;  w += (size_t)MM*HH*4;
  float*  tmp     = (float*)w;  w += (size_t)2*MM*HH*4;   // 2 split-K partials
  ushort* qkv_bf  = (ushort*)w; w += (size_t)3*MM*HH*2;
  ushort* x_bf    = (ushort*)w; w += (size_t)MM*HH*2;
  ushort* ctx_bf  = (ushort*)w; w += (size_t)MM*HH*2;
  ushort* hbuf_bf = (ushort*)w; w += (size_t)MM*FF*2;
  ushort* wbuf    = (ushort*)w; w += (size_t)(4*WQSZ + 2*W1SZ)*2;
  float*  rd      = (float*)w;  w += (size_t)MM*4;
  int*    seg     = (int*)w;    w += (size_t)MM*4;
  int*    vl      = (int*)w;    w += 64;

  prep_kernel<<<BB, 512, 0, stream>>>(am, bos, seg, vl);
  embed_ln_kernel<<<MM, 256, 0, stream>>>(word_emb, pos_emb, type_emb,
                                          emb_ln_g, emb_ln_b, input_ids, token_type, x, x_bf);

  dim3 gqkv(HH/64, MM/64, 3);     // 12 x 32 x 3 = 1152 blocks
  dim3 g_ff1(FF/64, MM/64, 1);    // 48 x 32     = 1536 blocks
  dim3 g_sk(HH/64, MM/64, 2);     // 12 x 32 x 2 =  768 blocks (split-K)
  dim3 gattn(LL/64, NH, BB);

  for (int l = 0; l < NL; l++) {
    convw_kernel<<<1728, 256, 0, stream>>>(Wq + (size_t)l*WQSZ, Wk + (size_t)l*WQSZ,
                                           Wv + (size_t)l*WQSZ, Wo + (size_t)l*WQSZ,
                                           W1 + (size_t)l*W1SZ, W2 + (size_t)l*W1SZ, wbuf);

    GArg3 gq;
    for (int z = 0; z < 3; z++) {
      gq.a[z].Bt   = wbuf + (size_t)z*WQSZ;
      gq.a[z].bias = (z == 0 ? bq : z == 1 ? bk : bv) + (size_t)l*HH;
      gq.a[z].Cf   = nullptr;
      gq.a[z].Cb   = qkv_bf + (size_t)z*MM*HH;
    }
    gemm_mfma64<0,0,1,0><<<gqkv, 256, 0, stream>>>(x_bf, gq, MM, HH, HH);

    attn_mfma_kernel<<<gattn, 256, 0, stream>>>(qkv_bf, qkv_bf + (size_t)MM*HH,
                                                qkv_bf + (size_t)2*MM*HH, ctx_bf, seg, vl, bos);

    GArg3 go = {};
    go.a[0].Bt = wbuf + (size_t)3*WQSZ; go.a[0].bias = bo + (size_t)l*HH;
    go.a[0].Cf = tmp; go.a[0].Cb = nullptr;
    gemm_mfma64<0,1,0,1><<<g_sk, 256, 0, stream>>>(ctx_bf, go, MM, HH, HH);

    add_ln2_kernel<<<MM, 256, 0, stream>>>(x, tmp, tmp + (size_t)MM*HH,
                                           attn_ln_g + (size_t)l*HH,
                                           attn_ln_b + (size_t)l*HH, x, x_bf);

    GArg3 g1 = {};
    g1.a[0].Bt = wbuf + (size_t)4*WQSZ; g1.a[0].bias = b1 + (size_t)l*FF;
    g1.a[0].Cf = nullptr; g1.a[0].Cb = hbuf_bf;
    gemm_mfma64<1,0,1,0><<<g_ff1, 256, 0, stream>>>(x_bf, g1, MM, FF, HH);

    GArg3 g2 = {};
    g2.a[0].Bt = wbuf + (size_t)4*WQSZ + W1SZ; g2.a[0].bias = b2 + (size_t)l*HH;
    g2.a[0].Cf = tmp; g2.a[0].Cb = nullptr;
    gemm_mfma64<0,1,0,1><<<g_sk, 256, 0, stream>>>(hbuf_bf, g2, MM, HH, FF);

    add_ln2_kernel<<<MM, 256, 0, stream>>>(x, tmp, tmp + (size_t)MM*HH,
                                           ffn_ln_g + (size_t)l*HH,
                                           ffn_ln_b + (size_t)l*HH, x, x_bf);
  }

  rowdot_kernel<<<MM, 256, 0, stream>>>(x, fc_w, rd);
  logits_kernel<<<1, 64, 0, stream>>>(rd, bos, vl, fc_b, out);
}